// Round 6
// baseline (414.395 us; speedup 1.0000x reference)
//
#include <hip/hip_runtime.h>

#define N_NODES 100000
#define ROWS_PAD 100096
#define NIN 512
#define H1  512
#define H2  128
#define N_EDGES 3200000

typedef __attribute__((ext_vector_type(8))) short bf16x8;
typedef __attribute__((ext_vector_type(4))) float f32x4;

__device__ __forceinline__ unsigned short f2b(float x) {
  union { float f; unsigned int u; } c; c.f = x;
  unsigned int u = c.u;
  unsigned int r = (u + 0x7FFFu + ((u >> 16) & 1u)) >> 16;
  return (unsigned short)r;
}
__device__ __forceinline__ float blo(unsigned u) {
  union { unsigned x; float f; } c; c.x = u << 16; return c.f;
}
__device__ __forceinline__ float bhi(unsigned u) {
  union { unsigned x; float f; } c; c.x = u & 0xffff0000u; return c.f;
}

typedef const __attribute__((address_space(1))) unsigned int* gp1_t;
typedef __attribute__((address_space(3))) unsigned int* sp3_t;
__device__ __forceinline__ void gl_lds16(const void* g, void* s) {
  __builtin_amdgcn_global_load_lds((gp1_t)g, (sp3_t)s, 16, 0, 0);
}

// ---- prep_a: seq_a f32 [N][512] -> A1 bf16 pre-swizzled: A1[n][k] = bf16(A[n][k ^ ((n&7)<<3)]) ----
__global__ void prep_a_kernel(const float* __restrict__ A, unsigned short* __restrict__ A1) {
  int idx = blockIdx.x * blockDim.x + threadIdx.x;
  int stride = gridDim.x * blockDim.x;
  for (int i = idx; i < N_NODES * 64; i += stride) {
    int n = i >> 6;
    int kb = (i & 63) << 3;
    int ks = kb ^ ((n & 7) << 3);
    const float* src = A + ((size_t)n << 9) + ks;
    float4 v0 = *(const float4*)src;
    float4 v1 = *(const float4*)(src + 4);
    uint4 p;
    p.x = (unsigned)f2b(v0.x) | ((unsigned)f2b(v0.y) << 16);
    p.y = (unsigned)f2b(v0.z) | ((unsigned)f2b(v0.w) << 16);
    p.z = (unsigned)f2b(v1.x) | ((unsigned)f2b(v1.y) << 16);
    p.w = (unsigned)f2b(v1.z) | ((unsigned)f2b(v1.w) << 16);
    *(uint4*)(A1 + ((size_t)n << 9) + kb) = p;
  }
}

// ---- prep_w: W transpose+bf16 pre-swizzled; + zero hp ----
__global__ void prep_w_kernel(const float* __restrict__ W1, const float* __restrict__ W2,
                              unsigned short* __restrict__ W1t, unsigned short* __restrict__ W2t,
                              float4* __restrict__ hp4) {
  int idx = blockIdx.x * blockDim.x + threadIdx.x;
  int stride = gridDim.x * blockDim.x;
  for (int i = idx; i < H1 * NIN; i += stride) {
    int n = i >> 9, k = i & 511;
    W1t[i] = f2b(W1[(size_t)(k ^ ((n & 7) << 3)) * H1 + n]);
  }
  for (int i = idx; i < H2 * H1; i += stride) {
    int n = i >> 9, k = i & 511;
    W2t[i] = f2b(W2[(size_t)(k ^ ((n & 7) << 3)) * H2 + n]);
  }
  float4 z; z.x = 0.f; z.y = 0.f; z.z = 0.f; z.w = 0.f;
  for (int i = idx; i < (N_NODES * H2) / 4; i += stride) hp4[i] = z;
}

// ---- GEMM1: h_pre = relu(A1 @ W1t^T + b1); 128x128, BK=64, 2-phase dbuf, XCD swizzle ----
__global__ __launch_bounds__(256, 2) void gemm1_kernel(
    const unsigned short* __restrict__ A1, const unsigned short* __restrict__ W1t,
    const float* __restrict__ b1, unsigned short* __restrict__ h_pre)
{
  __shared__ __align__(16) unsigned short Asm[2][128 * 64];
  __shared__ __align__(16) unsigned short Bsm[2][128 * 64];
  const int tid = threadIdx.x;
  const int w = tid >> 6, lane = tid & 63;
  const int l15 = lane & 15, lg = lane >> 4;
  const int wr = w & 1, wc = w >> 1;
  // bijective XCD swizzle: 3128 = 8 XCDs x 391; 4 column-blocks of a panel -> same XCD
  const int hw = blockIdx.x;
  const int work = (hw & 7) * 391 + (hw >> 3);
  const int row0 = (work >> 2) << 7;
  const int n0 = (work & 3) << 7;

  f32x4 acc[4][4];
  #pragma unroll
  for (int m = 0; m < 4; ++m)
    #pragma unroll
    for (int n = 0; n < 4; ++n) acc[m][n] = (f32x4){0.f, 0.f, 0.f, 0.f};

  const int so = w * 1024 + lane * 16;
  auto stage = [&](int kt, int b) {
    #pragma unroll
    for (int it = 0; it < 4; ++it) {
      int o = it * 4096 + so;
      int r = o >> 7, kb = o & 127;
      gl_lds16((const char*)A1 + (((size_t)(row0 + r)) << 10) + (kt << 7) + kb, (char*)(&Asm[b][0]) + o);
      gl_lds16((const char*)W1t + (((size_t)(n0 + r)) << 10) + (kt << 7) + kb, (char*)(&Bsm[b][0]) + o);
    }
  };

  stage(0, 0);
  #pragma unroll
  for (int kt = 0; kt < 8; ++kt) {
    const int cur = kt & 1;
    if (kt < 7) {
      stage(kt + 1, cur ^ 1);
      asm volatile("s_waitcnt vmcnt(8)" ::: "memory");   // wait cur's loads; kt+1's stay in flight
    } else {
      asm volatile("s_waitcnt vmcnt(0)" ::: "memory");
    }
    __builtin_amdgcn_s_barrier();
    asm volatile("" ::: "memory");
    #pragma unroll
    for (int ks = 0; ks < 2; ++ks) {
      bf16x8 af[4], bfr[4];
      #pragma unroll
      for (int m = 0; m < 4; ++m) {
        int r = wr * 64 + m * 16 + l15;
        af[m] = *(const bf16x8*)((const char*)(&Asm[cur][0]) + (r << 7) + (((ks << 6) + (lg << 4)) ^ ((r & 7) << 4)));
      }
      #pragma unroll
      for (int n = 0; n < 4; ++n) {
        int r = wc * 64 + n * 16 + l15;
        bfr[n] = *(const bf16x8*)((const char*)(&Bsm[cur][0]) + (r << 7) + (((ks << 6) + (lg << 4)) ^ ((r & 7) << 4)));
      }
      #pragma unroll
      for (int m = 0; m < 4; ++m)
        #pragma unroll
        for (int n = 0; n < 4; ++n)
          acc[m][n] = __builtin_amdgcn_mfma_f32_16x16x32_bf16(af[m], bfr[n], acc[m][n], 0, 0, 0);
    }
    asm volatile("" ::: "memory");
    __builtin_amdgcn_s_barrier();
  }

  #pragma unroll
  for (int n = 0; n < 4; ++n) {
    int col = n0 + wc * 64 + n * 16 + l15;
    float bias = b1[col];
    #pragma unroll
    for (int m = 0; m < 4; ++m) {
      #pragma unroll
      for (int q = 0; q < 4; ++q) {
        int row = row0 + wr * 64 + m * 16 + lg * 4 + q;
        if (row < N_NODES) {
          float v = acc[m][n][q] + bias;
          v = v > 0.f ? v : 0.f;
          h_pre[((size_t)row << 9) + (col ^ ((row & 7) << 3))] = f2b(v);
        }
      }
    }
  }
}

// ---- GEMM2: ha = h_pre @ W2 + b2 -> f32 d_out + bf16 gather table; 2-phase dbuf ----
__global__ __launch_bounds__(256, 2) void gemm2_kernel(
    const unsigned short* __restrict__ Hp, const unsigned short* __restrict__ W2t,
    const float* __restrict__ b2, float* __restrict__ ha_out, unsigned short* __restrict__ ha_bf)
{
  __shared__ __align__(16) unsigned short Asm[2][128 * 64];
  __shared__ __align__(16) unsigned short Bsm[2][128 * 64];
  const int tid = threadIdx.x;
  const int w = tid >> 6, lane = tid & 63;
  const int l15 = lane & 15, lg = lane >> 4;
  const int wr = w & 1, wc = w >> 1;
  const int row0 = blockIdx.x * 128;

  f32x4 acc[4][4];
  #pragma unroll
  for (int m = 0; m < 4; ++m)
    #pragma unroll
    for (int n = 0; n < 4; ++n) acc[m][n] = (f32x4){0.f, 0.f, 0.f, 0.f};

  const int so = w * 1024 + lane * 16;
  auto stage = [&](int kt, int b) {
    #pragma unroll
    for (int it = 0; it < 4; ++it) {
      int o = it * 4096 + so;
      int r = o >> 7, kb = o & 127;
      gl_lds16((const char*)Hp + (((size_t)(row0 + r)) << 10) + (kt << 7) + kb, (char*)(&Asm[b][0]) + o);
      gl_lds16((const char*)W2t + (((size_t)r) << 10) + (kt << 7) + kb, (char*)(&Bsm[b][0]) + o);
    }
  };

  stage(0, 0);
  #pragma unroll
  for (int kt = 0; kt < 8; ++kt) {
    const int cur = kt & 1;
    if (kt < 7) {
      stage(kt + 1, cur ^ 1);
      asm volatile("s_waitcnt vmcnt(8)" ::: "memory");
    } else {
      asm volatile("s_waitcnt vmcnt(0)" ::: "memory");
    }
    __builtin_amdgcn_s_barrier();
    asm volatile("" ::: "memory");
    #pragma unroll
    for (int ks = 0; ks < 2; ++ks) {
      bf16x8 af[4], bfr[4];
      #pragma unroll
      for (int m = 0; m < 4; ++m) {
        int r = wr * 64 + m * 16 + l15;
        af[m] = *(const bf16x8*)((const char*)(&Asm[cur][0]) + (r << 7) + (((ks << 6) + (lg << 4)) ^ ((r & 7) << 4)));
      }
      #pragma unroll
      for (int n = 0; n < 4; ++n) {
        int r = wc * 64 + n * 16 + l15;
        bfr[n] = *(const bf16x8*)((const char*)(&Bsm[cur][0]) + (r << 7) + (((ks << 6) + (lg << 4)) ^ ((r & 7) << 4)));
      }
      #pragma unroll
      for (int m = 0; m < 4; ++m)
        #pragma unroll
        for (int n = 0; n < 4; ++n)
          acc[m][n] = __builtin_amdgcn_mfma_f32_16x16x32_bf16(af[m], bfr[n], acc[m][n], 0, 0, 0);
    }
    asm volatile("" ::: "memory");
    __builtin_amdgcn_s_barrier();
  }

  #pragma unroll
  for (int n = 0; n < 4; ++n) {
    int col = wc * 64 + n * 16 + l15;
    float bias = b2[col];
    #pragma unroll
    for (int m = 0; m < 4; ++m) {
      #pragma unroll
      for (int q = 0; q < 4; ++q) {
        int row = row0 + wr * 64 + m * 16 + lg * 4 + q;
        if (row < N_NODES) {
          float v = acc[m][n][q] + bias;
          ha_out[((size_t)row << 7) + col] = v;
          ha_bf[((size_t)row << 7) + col] = f2b(v);
        }
      }
    }
  }
}

// ---- aggregation v4: bf16 table, 16-edge groups (16 gathers in flight), atomic-elision ----
__global__ __launch_bounds__(256) void agg_kernel(
    const int* __restrict__ rows, const int* __restrict__ cols, const float* __restrict__ vals,
    const unsigned short* __restrict__ ha_bf, float* __restrict__ hp)
{
  const int lane = threadIdx.x & 63;
  const int gw = (blockIdx.x * blockDim.x + threadIdx.x) >> 6;
  const int nw = (gridDim.x * blockDim.x) >> 6;
  int epw = (N_EDGES + nw - 1) / nw;
  epw = (epw + 15) & ~15;
  int e0 = gw * epw;
  if (e0 >= N_EDGES) return;
  int e1 = e0 + epw; if (e1 > N_EDGES) e1 = N_EDGES;
  const int ef = e0 + ((e1 - e0) & ~15);

  const unsigned* gt = (const unsigned*)ha_bf;   // [node][64] packed bf16 pairs
  const unsigned lx = (unsigned)lane;

  float acc0 = 0.f, acc1 = 0.f;
  int cur = rows[e0];
  bool first = true;

  auto flushrow = [&](int rr) {
    float* p = &hp[((size_t)cur << 7) + (lane << 1)];
    if (first) { atomicAdd(p, acc0); atomicAdd(p + 1, acc1); first = false; }
    else       { float2 st; st.x = acc0; st.y = acc1; *(float2*)p = st; }
    acc0 = 0.f; acc1 = 0.f; cur = rr;
  };

  for (int e = e0; e < ef; e += 16) {
    int rr[16]; int cc[16]; float vv[16];
    #pragma unroll
    for (int j = 0; j < 4; ++j) {
      int4   rv = *(const int4*)(rows + e + j * 4);
      int4   cv = *(const int4*)(cols + e + j * 4);
      float4 fv = *(const float4*)(vals + e + j * 4);
      rr[j*4+0] = rv.x; rr[j*4+1] = rv.y; rr[j*4+2] = rv.z; rr[j*4+3] = rv.w;
      cc[j*4+0] = cv.x; cc[j*4+1] = cv.y; cc[j*4+2] = cv.z; cc[j*4+3] = cv.w;
      vv[j*4+0] = fv.x; vv[j*4+1] = fv.y; vv[j*4+2] = fv.z; vv[j*4+3] = fv.w;
    }
    unsigned g[16];
    #pragma unroll
    for (int j = 0; j < 16; ++j) g[j] = gt[((size_t)cc[j] << 6) + lx];

    if (rr[0] == cur && rr[15] == cur) {           // whole group same row (sorted)
      float t0 = acc0, t1 = 0.f, t2 = 0.f, t3 = 0.f;
      float u0 = acc1, u1 = 0.f, u2 = 0.f, u3 = 0.f;
      #pragma unroll
      for (int j = 0; j < 16; j += 4) {
        t0 = fmaf(vv[j+0], blo(g[j+0]), t0);
        t1 = fmaf(vv[j+1], blo(g[j+1]), t1);
        t2 = fmaf(vv[j+2], blo(g[j+2]), t2);
        t3 = fmaf(vv[j+3], blo(g[j+3]), t3);
        u0 = fmaf(vv[j+0], bhi(g[j+0]), u0);
        u1 = fmaf(vv[j+1], bhi(g[j+1]), u1);
        u2 = fmaf(vv[j+2], bhi(g[j+2]), u2);
        u3 = fmaf(vv[j+3], bhi(g[j+3]), u3);
      }
      acc0 = (t0 + t1) + (t2 + t3);
      acc1 = (u0 + u1) + (u2 + u3);
    } else {
      #pragma unroll
      for (int j = 0; j < 16; ++j) {
        if (rr[j] != cur) flushrow(rr[j]);
        acc0 = fmaf(vv[j], blo(g[j]), acc0);
        acc1 = fmaf(vv[j], bhi(g[j]), acc1);
      }
    }
  }
  for (int e = ef; e < e1; ++e) {
    int r = rows[e];
    unsigned g = gt[((size_t)cols[e] << 6) + lx];
    if (r != cur) flushrow(r);
    float v = vals[e];
    acc0 = fmaf(v, blo(g), acc0);
    acc1 = fmaf(v, bhi(g), acc1);
  }
  atomicAdd(&hp[((size_t)cur << 7) + (lane << 1)], acc0);
  atomicAdd(&hp[((size_t)cur << 7) + (lane << 1) + 1], acc1);
}

extern "C" void kernel_launch(void* const* d_in, const int* in_sizes, int n_in,
                              void* d_out, int out_size, void* d_ws, size_t ws_size,
                              hipStream_t stream) {
  const float* seq_a    = (const float*)d_in[0];
  const float* W1       = (const float*)d_in[1];
  const float* b1       = (const float*)d_in[2];
  const float* W2       = (const float*)d_in[3];
  const float* b2       = (const float*)d_in[4];
  const int*   adj_rows = (const int*)d_in[5];
  const int*   adj_cols = (const int*)d_in[6];
  const float* adj_vals = (const float*)d_in[7];

  unsigned short* A1    = (unsigned short*)d_ws;            // ROWS_PAD x 512 bf16 (swizzled)
  unsigned short* h_pre = A1 + (size_t)ROWS_PAD * NIN;      // ROWS_PAD x 512 bf16 (swizzled)
  unsigned short* W1t   = h_pre + (size_t)ROWS_PAD * H1;    // 512 x 512 bf16
  unsigned short* W2t   = W1t + (size_t)H1 * NIN;           // 128 x 512 bf16
  unsigned short* ha_bf = W2t + (size_t)H2 * H1;            // N_NODES x 128 bf16

  float* ha_out = (float*)d_out;
  float* hp     = ha_out + (size_t)N_NODES * H2;

  prep_a_kernel<<<2048, 256, 0, stream>>>(seq_a, A1);
  prep_w_kernel<<<1280, 256, 0, stream>>>(W1, W2, W1t, W2t, (float4*)hp);
  gemm1_kernel<<<3128, 256, 0, stream>>>(A1, W1t, b1, h_pre);
  gemm2_kernel<<<782, 256, 0, stream>>>(h_pre, W2t, b2, ha_out, ha_bf);
  agg_kernel<<<2048, 256, 0, stream>>>(adj_rows, adj_cols, adj_vals, ha_bf, hp);
}

// Round 7
// 361.325 us; speedup vs baseline: 1.1469x; 1.1469x over previous
//
#include <hip/hip_runtime.h>

#define N_NODES 100000
#define ROWS_PAD 100096
#define NIN 512
#define H1  512
#define H2  128
#define N_EDGES 3200000

typedef __attribute__((ext_vector_type(8))) short bf16x8;
typedef __attribute__((ext_vector_type(4))) float f32x4;

__device__ __forceinline__ unsigned short f2b(float x) {
  union { float f; unsigned int u; } c; c.f = x;
  unsigned int u = c.u;
  unsigned int r = (u + 0x7FFFu + ((u >> 16) & 1u)) >> 16;
  return (unsigned short)r;
}
__device__ __forceinline__ float blo(unsigned u) {
  union { unsigned x; float f; } c; c.x = u << 16; return c.f;
}
__device__ __forceinline__ float bhi(unsigned u) {
  union { unsigned x; float f; } c; c.x = u & 0xffff0000u; return c.f;
}

typedef const __attribute__((address_space(1))) unsigned int* gp1_t;
typedef __attribute__((address_space(3))) unsigned int* sp3_t;
__device__ __forceinline__ void gl_lds16(const void* g, void* s) {
  __builtin_amdgcn_global_load_lds((gp1_t)g, (sp3_t)s, 16, 0, 0);
}

// ---- prep_a: seq_a f32 [N][512] -> A1 bf16 pre-swizzled ----
__global__ void prep_a_kernel(const float* __restrict__ A, unsigned short* __restrict__ A1) {
  int idx = blockIdx.x * blockDim.x + threadIdx.x;
  int stride = gridDim.x * blockDim.x;
  for (int i = idx; i < N_NODES * 64; i += stride) {
    int n = i >> 6;
    int kb = (i & 63) << 3;
    int ks = kb ^ ((n & 7) << 3);
    const float* src = A + ((size_t)n << 9) + ks;
    float4 v0 = *(const float4*)src;
    float4 v1 = *(const float4*)(src + 4);
    uint4 p;
    p.x = (unsigned)f2b(v0.x) | ((unsigned)f2b(v0.y) << 16);
    p.y = (unsigned)f2b(v0.z) | ((unsigned)f2b(v0.w) << 16);
    p.z = (unsigned)f2b(v1.x) | ((unsigned)f2b(v1.y) << 16);
    p.w = (unsigned)f2b(v1.z) | ((unsigned)f2b(v1.w) << 16);
    *(uint4*)(A1 + ((size_t)n << 9) + kb) = p;
  }
}

// ---- prep_w: W transpose+bf16 pre-swizzled ----
__global__ void prep_w_kernel(const float* __restrict__ W1, const float* __restrict__ W2,
                              unsigned short* __restrict__ W1t, unsigned short* __restrict__ W2t) {
  int idx = blockIdx.x * blockDim.x + threadIdx.x;
  int stride = gridDim.x * blockDim.x;
  for (int i = idx; i < H1 * NIN; i += stride) {
    int n = i >> 9, k = i & 511;
    W1t[i] = f2b(W1[(size_t)(k ^ ((n & 7) << 3)) * H1 + n]);
  }
  for (int i = idx; i < H2 * H1; i += stride) {
    int n = i >> 9, k = i & 511;
    W2t[i] = f2b(W2[(size_t)(k ^ ((n & 7) << 3)) * H2 + n]);
  }
}

// ---- rowptr: row_ptr[r] = first edge index with rows[e] >= r (rows sorted) ----
__global__ void rowptr_kernel(const int* __restrict__ rows, int* __restrict__ row_ptr) {
  int idx = blockIdx.x * blockDim.x + threadIdx.x;
  int stride = gridDim.x * blockDim.x;
  for (int e = idx; e < N_EDGES; e += stride) {
    int r = rows[e];
    int rp = (e == 0) ? -1 : rows[e - 1];
    for (int q = rp + 1; q <= r; ++q) row_ptr[q] = e;   // fills gaps (empty rows) too
  }
  int lastrow = rows[N_EDGES - 1];
  for (int q = idx; q <= N_NODES; q += stride)
    if (q > lastrow) row_ptr[q] = N_EDGES;
}

// ---- GEMM1: h_pre = relu(A1 @ W1t^T + b1); 128x128, BK=64, single-buffer, XCD swizzle ----
__global__ __launch_bounds__(256, 4) void gemm1_kernel(
    const unsigned short* __restrict__ A1, const unsigned short* __restrict__ W1t,
    const float* __restrict__ b1, unsigned short* __restrict__ h_pre)
{
  __shared__ __align__(16) unsigned short Asm[128 * 64];
  __shared__ __align__(16) unsigned short Bsm[128 * 64];
  const int tid = threadIdx.x;
  const int w = tid >> 6, lane = tid & 63;
  const int l15 = lane & 15, lg = lane >> 4;
  const int wr = w & 1, wc = w >> 1;
  // bijective XCD swizzle: 3128 = 8 XCDs x 391; 4 column-blocks of a panel -> same XCD
  const int hw = blockIdx.x;
  const int work = (hw & 7) * 391 + (hw >> 3);
  const int row0 = (work >> 2) << 7;
  const int n0 = (work & 3) << 7;

  f32x4 acc[4][4];
  #pragma unroll
  for (int m = 0; m < 4; ++m)
    #pragma unroll
    for (int n = 0; n < 4; ++n) acc[m][n] = (f32x4){0.f, 0.f, 0.f, 0.f};

  const int so = w * 1024 + lane * 16;
  for (int kt = 0; kt < 8; ++kt) {
    #pragma unroll
    for (int it = 0; it < 4; ++it) {
      int o = it * 4096 + so;
      int r = o >> 7, kb = o & 127;
      gl_lds16((const char*)A1 + (((size_t)(row0 + r)) << 10) + (kt << 7) + kb, (char*)Asm + o);
      gl_lds16((const char*)W1t + (((size_t)(n0 + r)) << 10) + (kt << 7) + kb, (char*)Bsm + o);
    }
    __syncthreads();
    #pragma unroll
    for (int ks = 0; ks < 2; ++ks) {
      bf16x8 af[4], bfr[4];
      #pragma unroll
      for (int m = 0; m < 4; ++m) {
        int r = wr * 64 + m * 16 + l15;
        af[m] = *(const bf16x8*)((const char*)Asm + (r << 7) + (((ks << 6) + (lg << 4)) ^ ((r & 7) << 4)));
      }
      #pragma unroll
      for (int n = 0; n < 4; ++n) {
        int r = wc * 64 + n * 16 + l15;
        bfr[n] = *(const bf16x8*)((const char*)Bsm + (r << 7) + (((ks << 6) + (lg << 4)) ^ ((r & 7) << 4)));
      }
      #pragma unroll
      for (int m = 0; m < 4; ++m)
        #pragma unroll
        for (int n = 0; n < 4; ++n)
          acc[m][n] = __builtin_amdgcn_mfma_f32_16x16x32_bf16(af[m], bfr[n], acc[m][n], 0, 0, 0);
    }
    __syncthreads();
  }

  #pragma unroll
  for (int n = 0; n < 4; ++n) {
    int col = n0 + wc * 64 + n * 16 + l15;
    float bias = b1[col];
    #pragma unroll
    for (int m = 0; m < 4; ++m) {
      #pragma unroll
      for (int q = 0; q < 4; ++q) {
        int row = row0 + wr * 64 + m * 16 + lg * 4 + q;
        if (row < N_NODES) {
          float v = acc[m][n][q] + bias;
          v = v > 0.f ? v : 0.f;
          h_pre[((size_t)row << 9) + (col ^ ((row & 7) << 3))] = f2b(v);
        }
      }
    }
  }
}

// ---- GEMM2: ha = h_pre @ W2 + b2 -> f32 d_out + bf16 gather table ----
__global__ __launch_bounds__(256, 4) void gemm2_kernel(
    const unsigned short* __restrict__ Hp, const unsigned short* __restrict__ W2t,
    const float* __restrict__ b2, float* __restrict__ ha_out, unsigned short* __restrict__ ha_bf)
{
  __shared__ __align__(16) unsigned short Asm[128 * 64];
  __shared__ __align__(16) unsigned short Bsm[128 * 64];
  const int tid = threadIdx.x;
  const int w = tid >> 6, lane = tid & 63;
  const int l15 = lane & 15, lg = lane >> 4;
  const int wr = w & 1, wc = w >> 1;
  const int row0 = blockIdx.x * 128;

  f32x4 acc[4][4];
  #pragma unroll
  for (int m = 0; m < 4; ++m)
    #pragma unroll
    for (int n = 0; n < 4; ++n) acc[m][n] = (f32x4){0.f, 0.f, 0.f, 0.f};

  const int so = w * 1024 + lane * 16;
  for (int kt = 0; kt < 8; ++kt) {
    #pragma unroll
    for (int it = 0; it < 4; ++it) {
      int o = it * 4096 + so;
      int r = o >> 7, kb = o & 127;
      gl_lds16((const char*)Hp + (((size_t)(row0 + r)) << 10) + (kt << 7) + kb, (char*)Asm + o);
      gl_lds16((const char*)W2t + (((size_t)r) << 10) + (kt << 7) + kb, (char*)Bsm + o);
    }
    __syncthreads();
    #pragma unroll
    for (int ks = 0; ks < 2; ++ks) {
      bf16x8 af[4], bfr[4];
      #pragma unroll
      for (int m = 0; m < 4; ++m) {
        int r = wr * 64 + m * 16 + l15;
        af[m] = *(const bf16x8*)((const char*)Asm + (r << 7) + (((ks << 6) + (lg << 4)) ^ ((r & 7) << 4)));
      }
      #pragma unroll
      for (int n = 0; n < 4; ++n) {
        int r = wc * 64 + n * 16 + l15;
        bfr[n] = *(const bf16x8*)((const char*)Bsm + (r << 7) + (((ks << 6) + (lg << 4)) ^ ((r & 7) << 4)));
      }
      #pragma unroll
      for (int m = 0; m < 4; ++m)
        #pragma unroll
        for (int n = 0; n < 4; ++n)
          acc[m][n] = __builtin_amdgcn_mfma_f32_16x16x32_bf16(af[m], bfr[n], acc[m][n], 0, 0, 0);
    }
    __syncthreads();
  }

  #pragma unroll
  for (int n = 0; n < 4; ++n) {
    int col = wc * 64 + n * 16 + l15;
    float bias = b2[col];
    #pragma unroll
    for (int m = 0; m < 4; ++m) {
      #pragma unroll
      for (int q = 0; q < 4; ++q) {
        int row = row0 + wr * 64 + m * 16 + lg * 4 + q;
        if (row < N_NODES) {
          float v = acc[m][n][q] + bias;
          ha_out[((size_t)row << 7) + col] = v;
          ha_bf[((size_t)row << 7) + col] = f2b(v);
        }
      }
    }
  }
}

// ---- aggregation v5: CSR, one wave per output row; no atomics, no branches ----
__global__ __launch_bounds__(256) void agg_csr_kernel(
    const int* __restrict__ row_ptr, const int* __restrict__ cols, const float* __restrict__ vals,
    const unsigned short* __restrict__ ha_bf, float* __restrict__ hp)
{
  const int row = __builtin_amdgcn_readfirstlane((blockIdx.x * blockDim.x + threadIdx.x) >> 6);
  if (row >= N_NODES) return;
  const int lane = threadIdx.x & 63;
  const int e0 = row_ptr[row];
  const int e1 = row_ptr[row + 1];
  const unsigned* gt = (const unsigned*)ha_bf;   // [node][64] packed bf16 pairs

  float acc0 = 0.f, acc1 = 0.f;
  int e = e0;
  for (; e + 8 <= e1; e += 8) {
    int   c[8]; float v[8]; unsigned g[8];
    #pragma unroll
    for (int j = 0; j < 8; ++j) { c[j] = cols[e + j]; v[j] = vals[e + j]; }
    #pragma unroll
    for (int j = 0; j < 8; ++j) g[j] = gt[((size_t)c[j] << 6) + lane];
    float t0 = acc0, t1 = 0.f, u0 = acc1, u1 = 0.f;
    #pragma unroll
    for (int j = 0; j < 8; j += 2) {
      t0 = fmaf(v[j+0], blo(g[j+0]), t0);
      t1 = fmaf(v[j+1], blo(g[j+1]), t1);
      u0 = fmaf(v[j+0], bhi(g[j+0]), u0);
      u1 = fmaf(v[j+1], bhi(g[j+1]), u1);
    }
    acc0 = t0 + t1; acc1 = u0 + u1;
  }
  for (; e < e1; ++e) {
    int c = cols[e];
    float v = vals[e];
    unsigned g = gt[((size_t)c << 6) + lane];
    acc0 = fmaf(v, blo(g), acc0);
    acc1 = fmaf(v, bhi(g), acc1);
  }
  float2 st; st.x = acc0; st.y = acc1;
  *(float2*)&hp[((size_t)row << 7) + (lane << 1)] = st;
}

extern "C" void kernel_launch(void* const* d_in, const int* in_sizes, int n_in,
                              void* d_out, int out_size, void* d_ws, size_t ws_size,
                              hipStream_t stream) {
  const float* seq_a    = (const float*)d_in[0];
  const float* W1       = (const float*)d_in[1];
  const float* b1       = (const float*)d_in[2];
  const float* W2       = (const float*)d_in[3];
  const float* b2       = (const float*)d_in[4];
  const int*   adj_rows = (const int*)d_in[5];
  const int*   adj_cols = (const int*)d_in[6];
  const float* adj_vals = (const float*)d_in[7];

  unsigned short* A1    = (unsigned short*)d_ws;            // ROWS_PAD x 512 bf16 (swizzled)
  unsigned short* h_pre = A1 + (size_t)ROWS_PAD * NIN;      // ROWS_PAD x 512 bf16 (swizzled)
  unsigned short* W1t   = h_pre + (size_t)ROWS_PAD * H1;    // 512 x 512 bf16
  unsigned short* W2t   = W1t + (size_t)H1 * NIN;           // 128 x 512 bf16
  unsigned short* ha_bf = W2t + (size_t)H2 * H1;            // N_NODES x 128 bf16
  int*            row_ptr = (int*)(ha_bf + (size_t)N_NODES * H2);  // N_NODES+1 int

  float* ha_out = (float*)d_out;
  float* hp     = ha_out + (size_t)N_NODES * H2;

  prep_a_kernel<<<2048, 256, 0, stream>>>(seq_a, A1);
  prep_w_kernel<<<1280, 256, 0, stream>>>(W1, W2, W1t, W2t);
  rowptr_kernel<<<2048, 256, 0, stream>>>(adj_rows, row_ptr);
  gemm1_kernel<<<3128, 256, 0, stream>>>(A1, W1t, b1, h_pre);
  gemm2_kernel<<<782, 256, 0, stream>>>(h_pre, W2t, b2, ha_out, ha_bf);
  agg_csr_kernel<<<(ROWS_PAD * 64) / 256, 256, 0, stream>>>(row_ptr, adj_cols, adj_vals, ha_bf, hp);
}

// Round 8
// 322.257 us; speedup vs baseline: 1.2859x; 1.1212x over previous
//
#include <hip/hip_runtime.h>

#define N_NODES 100000
#define ROWS_PAD 100096
#define NIN 512
#define H1  512
#define H2  128
#define N_EDGES 3200000

typedef __attribute__((ext_vector_type(8))) short bf16x8;
typedef __attribute__((ext_vector_type(4))) float f32x4;

__device__ __forceinline__ unsigned short f2b(float x) {
  union { float f; unsigned int u; } c; c.f = x;
  unsigned int u = c.u;
  unsigned int r = (u + 0x7FFFu + ((u >> 16) & 1u)) >> 16;
  return (unsigned short)r;
}
__device__ __forceinline__ float blo(unsigned u) {
  union { unsigned x; float f; } c; c.x = u << 16; return c.f;
}
__device__ __forceinline__ float bhi(unsigned u) {
  union { unsigned x; float f; } c; c.x = u & 0xffff0000u; return c.f;
}

typedef const __attribute__((address_space(1))) unsigned int* gp1_t;
typedef __attribute__((address_space(3))) unsigned int* sp3_t;
__device__ __forceinline__ void gl_lds16(const void* g, void* s) {
  __builtin_amdgcn_global_load_lds((gp1_t)g, (sp3_t)s, 16, 0, 0);
}

// ---- prep_a: seq_a f32 [N][512] -> A1 bf16 pre-swizzled ----
__global__ void prep_a_kernel(const float* __restrict__ A, unsigned short* __restrict__ A1) {
  int idx = blockIdx.x * blockDim.x + threadIdx.x;
  int stride = gridDim.x * blockDim.x;
  for (int i = idx; i < N_NODES * 64; i += stride) {
    int n = i >> 6;
    int kb = (i & 63) << 3;
    int ks = kb ^ ((n & 7) << 3);
    const float* src = A + ((size_t)n << 9) + ks;
    float4 v0 = *(const float4*)src;
    float4 v1 = *(const float4*)(src + 4);
    uint4 p;
    p.x = (unsigned)f2b(v0.x) | ((unsigned)f2b(v0.y) << 16);
    p.y = (unsigned)f2b(v0.z) | ((unsigned)f2b(v0.w) << 16);
    p.z = (unsigned)f2b(v1.x) | ((unsigned)f2b(v1.y) << 16);
    p.w = (unsigned)f2b(v1.z) | ((unsigned)f2b(v1.w) << 16);
    *(uint4*)(A1 + ((size_t)n << 9) + kb) = p;
  }
}

// ---- prep_w: W transpose+bf16 pre-swizzled ----
__global__ void prep_w_kernel(const float* __restrict__ W1, const float* __restrict__ W2,
                              unsigned short* __restrict__ W1t, unsigned short* __restrict__ W2t) {
  int idx = blockIdx.x * blockDim.x + threadIdx.x;
  int stride = gridDim.x * blockDim.x;
  for (int i = idx; i < H1 * NIN; i += stride) {
    int n = i >> 9, k = i & 511;
    W1t[i] = f2b(W1[(size_t)(k ^ ((n & 7) << 3)) * H1 + n]);
  }
  for (int i = idx; i < H2 * H1; i += stride) {
    int n = i >> 9, k = i & 511;
    W2t[i] = f2b(W2[(size_t)(k ^ ((n & 7) << 3)) * H2 + n]);
  }
}

// ---- rowptr: row_ptr[r] = first edge index with rows[e] >= r (rows sorted) ----
__global__ void rowptr_kernel(const int* __restrict__ rows, int* __restrict__ row_ptr) {
  int idx = blockIdx.x * blockDim.x + threadIdx.x;
  int stride = gridDim.x * blockDim.x;
  for (int e = idx; e < N_EDGES; e += stride) {
    int r = rows[e];
    int rp = (e == 0) ? -1 : rows[e - 1];
    for (int q = rp + 1; q <= r; ++q) row_ptr[q] = e;
  }
  int lastrow = rows[N_EDGES - 1];
  for (int q = idx; q <= N_NODES; q += stride)
    if (q > lastrow) row_ptr[q] = N_EDGES;
}

// ---- GEMM1: h_pre = relu(A1 @ W1t^T + b1); 64x128 tile, BK=64, XCD swizzle, repack epilogue ----
__global__ __launch_bounds__(256, 5) void gemm1_kernel(
    const unsigned short* __restrict__ A1, const unsigned short* __restrict__ W1t,
    const float* __restrict__ b1, unsigned short* __restrict__ h_pre)
{
  __shared__ __align__(16) unsigned short SM[12288];   // 24 KB: A[0..4095], B[4096..12287]
  const int tid = threadIdx.x;
  const int w = tid >> 6, lane = tid & 63;
  const int l15 = lane & 15, lg = lane >> 4;
  const int wr = w & 1, wc = w >> 1;                   // 2 row-groups x 2 col-groups
  // bijective XCD swizzle: 6256 = 8 x 782; 4 col-blocks of a row-panel -> same XCD
  const int hw = blockIdx.x;
  const int work = (hw & 7) * 782 + (hw >> 3);
  const int row0 = (work >> 2) << 6;
  const int n0 = (work & 3) << 7;

  f32x4 acc[2][4];
  #pragma unroll
  for (int m = 0; m < 2; ++m)
    #pragma unroll
    for (int n = 0; n < 4; ++n) acc[m][n] = (f32x4){0.f, 0.f, 0.f, 0.f};

  const int so = tid * 16;
  for (int kt = 0; kt < 8; ++kt) {
    #pragma unroll
    for (int it = 0; it < 2; ++it) {                   // A: 64 rows x 64 k
      int o = it * 4096 + so;
      int r = o >> 7, kb = o & 127;
      gl_lds16((const char*)A1 + (((size_t)(row0 + r)) << 10) + (kt << 7) + kb, (char*)SM + o);
    }
    #pragma unroll
    for (int it = 0; it < 4; ++it) {                   // B: 128 n x 64 k
      int o = it * 4096 + so;
      int r = o >> 7, kb = o & 127;
      gl_lds16((const char*)W1t + (((size_t)(n0 + r)) << 10) + (kt << 7) + kb, (char*)SM + 8192 + o);
    }
    __syncthreads();
    #pragma unroll
    for (int ks = 0; ks < 2; ++ks) {
      bf16x8 af[2], bfr[4];
      #pragma unroll
      for (int m = 0; m < 2; ++m) {
        int r = wr * 32 + m * 16 + l15;
        af[m] = *(const bf16x8*)((const char*)SM + (r << 7) + (((ks << 6) + (lg << 4)) ^ ((r & 7) << 4)));
      }
      #pragma unroll
      for (int n = 0; n < 4; ++n) {
        int r = wc * 64 + n * 16 + l15;
        bfr[n] = *(const bf16x8*)((const char*)SM + 8192 + (r << 7) + (((ks << 6) + (lg << 4)) ^ ((r & 7) << 4)));
      }
      #pragma unroll
      for (int m = 0; m < 2; ++m)
        #pragma unroll
        for (int n = 0; n < 4; ++n)
          acc[m][n] = __builtin_amdgcn_mfma_f32_16x16x32_bf16(af[m], bfr[n], acc[m][n], 0, 0, 0);
    }
    __syncthreads();
  }

  // ---- epilogue: bias+relu -> bf16 T (pre-swizzled layout) in LDS, then 16B coalesced stores ----
  #pragma unroll
  for (int n = 0; n < 4; ++n) {
    int cl = wc * 64 + n * 16 + l15;
    float bias = b1[n0 + cl];
    #pragma unroll
    for (int m = 0; m < 2; ++m) {
      #pragma unroll
      for (int q = 0; q < 4; ++q) {
        int rl = wr * 32 + m * 16 + lg * 4 + q;
        float v = acc[m][n][q] + bias;
        v = v > 0.f ? v : 0.f;
        SM[rl * 128 + (cl ^ ((rl & 7) << 3))] = f2b(v);
      }
    }
  }
  __syncthreads();
  #pragma unroll
  for (int p = 0; p < 4; ++p) {
    int ch = tid + p * 256;                            // 16B chunk id; row = ch>>4
    int row = ch >> 4, six = ch & 15;
    uint4 d = *(const uint4*)((const char*)SM + (ch << 4));
    *(uint4*)((char*)h_pre + (((size_t)(row0 + row)) << 10) + (n0 << 1) + (six << 4)) = d;
  }
}

// ---- GEMM2: ha = h_pre @ W2 + b2 -> f32 d_out + bf16 gather table; 64x128 tile ----
__global__ __launch_bounds__(256, 5) void gemm2_kernel(
    const unsigned short* __restrict__ Hp, const unsigned short* __restrict__ W2t,
    const float* __restrict__ b2, float* __restrict__ ha_out, unsigned short* __restrict__ ha_bf)
{
  __shared__ __align__(16) unsigned short SM[12288];   // A[0..4095], B[4096..12287]
  const int tid = threadIdx.x;
  const int w = tid >> 6, lane = tid & 63;
  const int l15 = lane & 15, lg = lane >> 4;
  const int wr = w & 1, wc = w >> 1;
  const int row0 = blockIdx.x << 6;

  f32x4 acc[2][4];
  #pragma unroll
  for (int m = 0; m < 2; ++m)
    #pragma unroll
    for (int n = 0; n < 4; ++n) acc[m][n] = (f32x4){0.f, 0.f, 0.f, 0.f};

  const int so = tid * 16;
  for (int kt = 0; kt < 8; ++kt) {
    #pragma unroll
    for (int it = 0; it < 2; ++it) {
      int o = it * 4096 + so;
      int r = o >> 7, kb = o & 127;
      gl_lds16((const char*)Hp + (((size_t)(row0 + r)) << 10) + (kt << 7) + kb, (char*)SM + o);
    }
    #pragma unroll
    for (int it = 0; it < 4; ++it) {
      int o = it * 4096 + so;
      int r = o >> 7, kb = o & 127;
      gl_lds16((const char*)W2t + (((size_t)r) << 10) + (kt << 7) + kb, (char*)SM + 8192 + o);
    }
    __syncthreads();
    #pragma unroll
    for (int ks = 0; ks < 2; ++ks) {
      bf16x8 af[2], bfr[4];
      #pragma unroll
      for (int m = 0; m < 2; ++m) {
        int r = wr * 32 + m * 16 + l15;
        af[m] = *(const bf16x8*)((const char*)SM + (r << 7) + (((ks << 6) + (lg << 4)) ^ ((r & 7) << 4)));
      }
      #pragma unroll
      for (int n = 0; n < 4; ++n) {
        int r = wc * 64 + n * 16 + l15;
        bfr[n] = *(const bf16x8*)((const char*)SM + 8192 + (r << 7) + (((ks << 6) + (lg << 4)) ^ ((r & 7) << 4)));
      }
      #pragma unroll
      for (int m = 0; m < 2; ++m)
        #pragma unroll
        for (int n = 0; n < 4; ++n)
          acc[m][n] = __builtin_amdgcn_mfma_f32_16x16x32_bf16(af[m], bfr[n], acc[m][n], 0, 0, 0);
    }
    __syncthreads();
  }

  #pragma unroll
  for (int n = 0; n < 4; ++n) {
    int col = wc * 64 + n * 16 + l15;
    float bias = b2[col];
    #pragma unroll
    for (int m = 0; m < 2; ++m) {
      #pragma unroll
      for (int q = 0; q < 4; ++q) {
        int row = row0 + wr * 32 + m * 16 + lg * 4 + q;
        if (row < N_NODES) {
          float v = acc[m][n][q] + bias;
          ha_out[((size_t)row << 7) + col] = v;
          ha_bf[((size_t)row << 7) + col] = f2b(v);
        }
      }
    }
  }
}

// ---- aggregation: CSR, one wave per output row; no atomics, no branches ----
__global__ __launch_bounds__(256) void agg_csr_kernel(
    const int* __restrict__ row_ptr, const int* __restrict__ cols, const float* __restrict__ vals,
    const unsigned short* __restrict__ ha_bf, float* __restrict__ hp)
{
  const int row = __builtin_amdgcn_readfirstlane((blockIdx.x * blockDim.x + threadIdx.x) >> 6);
  if (row >= N_NODES) return;
  const int lane = threadIdx.x & 63;
  const int e0 = row_ptr[row];
  const int e1 = row_ptr[row + 1];
  const unsigned* gt = (const unsigned*)ha_bf;

  float acc0 = 0.f, acc1 = 0.f;
  int e = e0;
  for (; e + 8 <= e1; e += 8) {
    int   c[8]; float v[8]; unsigned g[8];
    #pragma unroll
    for (int j = 0; j < 8; ++j) { c[j] = cols[e + j]; v[j] = vals[e + j]; }
    #pragma unroll
    for (int j = 0; j < 8; ++j) g[j] = gt[((size_t)c[j] << 6) + lane];
    float t0 = acc0, t1 = 0.f, u0 = acc1, u1 = 0.f;
    #pragma unroll
    for (int j = 0; j < 8; j += 2) {
      t0 = fmaf(v[j+0], blo(g[j+0]), t0);
      t1 = fmaf(v[j+1], blo(g[j+1]), t1);
      u0 = fmaf(v[j+0], bhi(g[j+0]), u0);
      u1 = fmaf(v[j+1], bhi(g[j+1]), u1);
    }
    acc0 = t0 + t1; acc1 = u0 + u1;
  }
  for (; e < e1; ++e) {
    int c = cols[e];
    float v = vals[e];
    unsigned g = gt[((size_t)c << 6) + lane];
    acc0 = fmaf(v, blo(g), acc0);
    acc1 = fmaf(v, bhi(g), acc1);
  }
  float2 st; st.x = acc0; st.y = acc1;
  *(float2*)&hp[((size_t)row << 7) + (lane << 1)] = st;
}

extern "C" void kernel_launch(void* const* d_in, const int* in_sizes, int n_in,
                              void* d_out, int out_size, void* d_ws, size_t ws_size,
                              hipStream_t stream) {
  const float* seq_a    = (const float*)d_in[0];
  const float* W1       = (const float*)d_in[1];
  const float* b1       = (const float*)d_in[2];
  const float* W2       = (const float*)d_in[3];
  const float* b2       = (const float*)d_in[4];
  const int*   adj_rows = (const int*)d_in[5];
  const int*   adj_cols = (const int*)d_in[6];
  const float* adj_vals = (const float*)d_in[7];

  unsigned short* A1    = (unsigned short*)d_ws;            // ROWS_PAD x 512 bf16 (swizzled)
  unsigned short* h_pre = A1 + (size_t)ROWS_PAD * NIN;      // ROWS_PAD x 512 bf16 (swizzled)
  unsigned short* W1t   = h_pre + (size_t)ROWS_PAD * H1;    // 512 x 512 bf16
  unsigned short* W2t   = W1t + (size_t)H1 * NIN;           // 128 x 512 bf16
  unsigned short* ha_bf = W2t + (size_t)H2 * H1;            // N_NODES x 128 bf16
  int*            row_ptr = (int*)(ha_bf + (size_t)N_NODES * H2);  // N_NODES+1 int

  float* ha_out = (float*)d_out;
  float* hp     = ha_out + (size_t)N_NODES * H2;

  prep_a_kernel<<<2048, 256, 0, stream>>>(seq_a, A1);
  prep_w_kernel<<<1280, 256, 0, stream>>>(W1, W2, W1t, W2t);
  rowptr_kernel<<<2048, 256, 0, stream>>>(adj_rows, row_ptr);
  gemm1_kernel<<<6256, 256, 0, stream>>>(A1, W1t, b1, h_pre);
  gemm2_kernel<<<1564, 256, 0, stream>>>(h_pre, W2t, b2, ha_out, ha_bf);
  agg_csr_kernel<<<(ROWS_PAD * 64) / 256, 256, 0, stream>>>(row_ptr, adj_cols, adj_vals, ha_bf, hp);
}

// Round 9
// 301.679 us; speedup vs baseline: 1.3736x; 1.0682x over previous
//
#include <hip/hip_runtime.h>

#define N_NODES 100000
#define ROWS_PAD 100096
#define NIN 512
#define H1  512
#define H2  128
#define N_EDGES 3200000

typedef __attribute__((ext_vector_type(8))) short bf16x8;
typedef __attribute__((ext_vector_type(4))) float f32x4;
typedef __attribute__((ext_vector_type(2))) float f32x2;

__device__ __forceinline__ unsigned short f2b(float x) {
  union { float f; unsigned int u; } c; c.f = x;
  unsigned int u = c.u;
  unsigned int r = (u + 0x7FFFu + ((u >> 16) & 1u)) >> 16;
  return (unsigned short)r;
}

typedef const __attribute__((address_space(1))) unsigned int* gp1_t;
typedef __attribute__((address_space(3))) unsigned int* sp3_t;
__device__ __forceinline__ void gl_lds16(const void* g, void* s) {
  __builtin_amdgcn_global_load_lds((gp1_t)g, (sp3_t)s, 16, 0, 0);
}

// ---- prep_a: seq_a f32 [N][512] -> A1 bf16 pre-swizzled ----
__global__ void prep_a_kernel(const float* __restrict__ A, unsigned short* __restrict__ A1) {
  int idx = blockIdx.x * blockDim.x + threadIdx.x;
  int stride = gridDim.x * blockDim.x;
  for (int i = idx; i < N_NODES * 64; i += stride) {
    int n = i >> 6;
    int kb = (i & 63) << 3;
    int ks = kb ^ ((n & 7) << 3);
    const float* src = A + ((size_t)n << 9) + ks;
    float4 v0 = *(const float4*)src;
    float4 v1 = *(const float4*)(src + 4);
    uint4 p;
    p.x = (unsigned)f2b(v0.x) | ((unsigned)f2b(v0.y) << 16);
    p.y = (unsigned)f2b(v0.z) | ((unsigned)f2b(v0.w) << 16);
    p.z = (unsigned)f2b(v1.x) | ((unsigned)f2b(v1.y) << 16);
    p.w = (unsigned)f2b(v1.z) | ((unsigned)f2b(v1.w) << 16);
    *(uint4*)(A1 + ((size_t)n << 9) + kb) = p;
  }
}

// ---- prep_w: W transpose+bf16 pre-swizzled ----
__global__ void prep_w_kernel(const float* __restrict__ W1, const float* __restrict__ W2,
                              unsigned short* __restrict__ W1t, unsigned short* __restrict__ W2t) {
  int idx = blockIdx.x * blockDim.x + threadIdx.x;
  int stride = gridDim.x * blockDim.x;
  for (int i = idx; i < H1 * NIN; i += stride) {
    int n = i >> 9, k = i & 511;
    W1t[i] = f2b(W1[(size_t)(k ^ ((n & 7) << 3)) * H1 + n]);
  }
  for (int i = idx; i < H2 * H1; i += stride) {
    int n = i >> 9, k = i & 511;
    W2t[i] = f2b(W2[(size_t)(k ^ ((n & 7) << 3)) * H2 + n]);
  }
}

// ---- rowptr: row_ptr[r] = first edge index with rows[e] >= r (rows sorted) ----
__global__ void rowptr_kernel(const int* __restrict__ rows, int* __restrict__ row_ptr) {
  int idx = blockIdx.x * blockDim.x + threadIdx.x;
  int stride = gridDim.x * blockDim.x;
  for (int e = idx; e < N_EDGES; e += stride) {
    int r = rows[e];
    int rp = (e == 0) ? -1 : rows[e - 1];
    for (int q = rp + 1; q <= r; ++q) row_ptr[q] = e;
  }
  int lastrow = rows[N_EDGES - 1];
  for (int q = idx; q <= N_NODES; q += stride)
    if (q > lastrow) row_ptr[q] = N_EDGES;
}

// ---- GEMM1: h_pre = relu(A1 @ W1t^T + b1); 64x128 tile, BK=64, XCD swizzle, repack epilogue ----
__global__ __launch_bounds__(256, 5) void gemm1_kernel(
    const unsigned short* __restrict__ A1, const unsigned short* __restrict__ W1t,
    const float* __restrict__ b1, unsigned short* __restrict__ h_pre)
{
  __shared__ __align__(16) unsigned short SM[12288];   // 24 KB: A[0..4095], B[4096..12287]
  const int tid = threadIdx.x;
  const int w = tid >> 6, lane = tid & 63;
  const int l15 = lane & 15, lg = lane >> 4;
  const int wr = w & 1, wc = w >> 1;
  // bijective XCD swizzle: 6256 = 8 x 782; 4 col-blocks of a row-panel -> same XCD
  const int hw = blockIdx.x;
  const int work = (hw & 7) * 782 + (hw >> 3);
  const int row0 = (work >> 2) << 6;
  const int n0 = (work & 3) << 7;

  f32x4 acc[2][4];
  #pragma unroll
  for (int m = 0; m < 2; ++m)
    #pragma unroll
    for (int n = 0; n < 4; ++n) acc[m][n] = (f32x4){0.f, 0.f, 0.f, 0.f};

  const int so = tid * 16;
  for (int kt = 0; kt < 8; ++kt) {
    #pragma unroll
    for (int it = 0; it < 2; ++it) {
      int o = it * 4096 + so;
      int r = o >> 7, kb = o & 127;
      gl_lds16((const char*)A1 + (((size_t)(row0 + r)) << 10) + (kt << 7) + kb, (char*)SM + o);
    }
    #pragma unroll
    for (int it = 0; it < 4; ++it) {
      int o = it * 4096 + so;
      int r = o >> 7, kb = o & 127;
      gl_lds16((const char*)W1t + (((size_t)(n0 + r)) << 10) + (kt << 7) + kb, (char*)SM + 8192 + o);
    }
    __syncthreads();
    #pragma unroll
    for (int ks = 0; ks < 2; ++ks) {
      bf16x8 af[2], bfr[4];
      #pragma unroll
      for (int m = 0; m < 2; ++m) {
        int r = wr * 32 + m * 16 + l15;
        af[m] = *(const bf16x8*)((const char*)SM + (r << 7) + (((ks << 6) + (lg << 4)) ^ ((r & 7) << 4)));
      }
      #pragma unroll
      for (int n = 0; n < 4; ++n) {
        int r = wc * 64 + n * 16 + l15;
        bfr[n] = *(const bf16x8*)((const char*)SM + 8192 + (r << 7) + (((ks << 6) + (lg << 4)) ^ ((r & 7) << 4)));
      }
      #pragma unroll
      for (int m = 0; m < 2; ++m)
        #pragma unroll
        for (int n = 0; n < 4; ++n)
          acc[m][n] = __builtin_amdgcn_mfma_f32_16x16x32_bf16(af[m], bfr[n], acc[m][n], 0, 0, 0);
    }
    __syncthreads();
  }

  // ---- epilogue: bias+relu -> bf16 (pre-swizzled layout) in LDS, then 16B coalesced stores ----
  #pragma unroll
  for (int n = 0; n < 4; ++n) {
    int cl = wc * 64 + n * 16 + l15;
    float bias = b1[n0 + cl];
    #pragma unroll
    for (int m = 0; m < 2; ++m) {
      #pragma unroll
      for (int q = 0; q < 4; ++q) {
        int rl = wr * 32 + m * 16 + lg * 4 + q;
        float v = acc[m][n][q] + bias;
        v = v > 0.f ? v : 0.f;
        SM[rl * 128 + (cl ^ ((rl & 7) << 3))] = f2b(v);
      }
    }
  }
  __syncthreads();
  #pragma unroll
  for (int p = 0; p < 4; ++p) {
    int ch = tid + p * 256;
    int row = ch >> 4, six = ch & 15;
    uint4 d = *(const uint4*)((const char*)SM + (ch << 4));
    *(uint4*)((char*)h_pre + (((size_t)(row0 + row)) << 10) + (n0 << 1) + (six << 4)) = d;
  }
}

// ---- GEMM2: ha = h_pre @ W2 + b2 -> f32 d_out + fp8 e4m3 gather table; 64x128 tile ----
__global__ __launch_bounds__(256, 5) void gemm2_kernel(
    const unsigned short* __restrict__ Hp, const unsigned short* __restrict__ W2t,
    const float* __restrict__ b2, float* __restrict__ ha_out, unsigned char* __restrict__ ha8)
{
  __shared__ __align__(16) unsigned short SM[12288];
  const int tid = threadIdx.x;
  const int w = tid >> 6, lane = tid & 63;
  const int l15 = lane & 15, lg = lane >> 4;
  const int wr = w & 1, wc = w >> 1;
  const int row0 = blockIdx.x << 6;

  f32x4 acc[2][4];
  #pragma unroll
  for (int m = 0; m < 2; ++m)
    #pragma unroll
    for (int n = 0; n < 4; ++n) acc[m][n] = (f32x4){0.f, 0.f, 0.f, 0.f};

  const int so = tid * 16;
  for (int kt = 0; kt < 8; ++kt) {
    #pragma unroll
    for (int it = 0; it < 2; ++it) {
      int o = it * 4096 + so;
      int r = o >> 7, kb = o & 127;
      gl_lds16((const char*)Hp + (((size_t)(row0 + r)) << 10) + (kt << 7) + kb, (char*)SM + o);
    }
    #pragma unroll
    for (int it = 0; it < 4; ++it) {
      int o = it * 4096 + so;
      int r = o >> 7, kb = o & 127;
      gl_lds16((const char*)W2t + (((size_t)r) << 10) + (kt << 7) + kb, (char*)SM + 8192 + o);
    }
    __syncthreads();
    #pragma unroll
    for (int ks = 0; ks < 2; ++ks) {
      bf16x8 af[2], bfr[4];
      #pragma unroll
      for (int m = 0; m < 2; ++m) {
        int r = wr * 32 + m * 16 + l15;
        af[m] = *(const bf16x8*)((const char*)SM + (r << 7) + (((ks << 6) + (lg << 4)) ^ ((r & 7) << 4)));
      }
      #pragma unroll
      for (int n = 0; n < 4; ++n) {
        int r = wc * 64 + n * 16 + l15;
        bfr[n] = *(const bf16x8*)((const char*)SM + 8192 + (r << 7) + (((ks << 6) + (lg << 4)) ^ ((r & 7) << 4)));
      }
      #pragma unroll
      for (int m = 0; m < 2; ++m)
        #pragma unroll
        for (int n = 0; n < 4; ++n)
          acc[m][n] = __builtin_amdgcn_mfma_f32_16x16x32_bf16(af[m], bfr[n], acc[m][n], 0, 0, 0);
    }
    __syncthreads();
  }

  #pragma unroll
  for (int n = 0; n < 4; ++n) {
    int col = wc * 64 + n * 16 + l15;
    float bias = b2[col];
    #pragma unroll
    for (int m = 0; m < 2; ++m) {
      #pragma unroll
      for (int q = 0; q < 4; ++q) {
        int row = row0 + wr * 32 + m * 16 + lg * 4 + q;
        if (row < N_NODES) {
          float v = acc[m][n][q] + bias;
          ha_out[((size_t)row << 7) + col] = v;
          int p8 = __builtin_amdgcn_cvt_pk_fp8_f32(v, v, 0, false);
          ha8[((size_t)row << 7) + col] = (unsigned char)(p8 & 0xff);
        }
      }
    }
  }
}

// ---- aggregation: CSR, one wave per row, fp8 table (2 cache lines/edge), no atomics ----
__global__ __launch_bounds__(256) void agg_csr_kernel(
    const int* __restrict__ row_ptr, const int* __restrict__ cols, const float* __restrict__ vals,
    const unsigned char* __restrict__ gtab8, float* __restrict__ hp)
{
  const int row = __builtin_amdgcn_readfirstlane((blockIdx.x * blockDim.x + threadIdx.x) >> 6);
  if (row >= N_NODES) return;
  const int lane = threadIdx.x & 63;
  const int e0 = row_ptr[row];
  const int e1 = row_ptr[row + 1];

  float acc0 = 0.f, acc1 = 0.f;
  int e = e0;
  for (; e + 8 <= e1; e += 8) {
    int c[8]; float v[8]; unsigned short g[8];
    #pragma unroll
    for (int j = 0; j < 8; ++j) { c[j] = cols[e + j]; v[j] = vals[e + j]; }
    #pragma unroll
    for (int j = 0; j < 8; ++j)
      g[j] = *(const unsigned short*)(gtab8 + ((size_t)c[j] << 7) + (lane << 1));
    float t0 = acc0, t1 = 0.f, u0 = acc1, u1 = 0.f;
    #pragma unroll
    for (int j = 0; j < 8; j += 2) {
      f32x2 f0 = __builtin_amdgcn_cvt_pk_f32_fp8((int)g[j+0], false);
      f32x2 f1 = __builtin_amdgcn_cvt_pk_f32_fp8((int)g[j+1], false);
      t0 = fmaf(v[j+0], f0.x, t0);
      t1 = fmaf(v[j+1], f1.x, t1);
      u0 = fmaf(v[j+0], f0.y, u0);
      u1 = fmaf(v[j+1], f1.y, u1);
    }
    acc0 = t0 + t1; acc1 = u0 + u1;
  }
  for (; e < e1; ++e) {
    int c = cols[e];
    float v = vals[e];
    unsigned short g = *(const unsigned short*)(gtab8 + ((size_t)c << 7) + (lane << 1));
    f32x2 f = __builtin_amdgcn_cvt_pk_f32_fp8((int)g, false);
    acc0 = fmaf(v, f.x, acc0);
    acc1 = fmaf(v, f.y, acc1);
  }
  float2 st; st.x = acc0; st.y = acc1;
  *(float2*)&hp[((size_t)row << 7) + (lane << 1)] = st;
}

extern "C" void kernel_launch(void* const* d_in, const int* in_sizes, int n_in,
                              void* d_out, int out_size, void* d_ws, size_t ws_size,
                              hipStream_t stream) {
  const float* seq_a    = (const float*)d_in[0];
  const float* W1       = (const float*)d_in[1];
  const float* b1       = (const float*)d_in[2];
  const float* W2       = (const float*)d_in[3];
  const float* b2       = (const float*)d_in[4];
  const int*   adj_rows = (const int*)d_in[5];
  const int*   adj_cols = (const int*)d_in[6];
  const float* adj_vals = (const float*)d_in[7];

  unsigned short* A1    = (unsigned short*)d_ws;            // ROWS_PAD x 512 bf16 (swizzled)
  unsigned short* h_pre = A1 + (size_t)ROWS_PAD * NIN;      // ROWS_PAD x 512 bf16 (swizzled)
  unsigned short* W1t   = h_pre + (size_t)ROWS_PAD * H1;    // 512 x 512 bf16
  unsigned short* W2t   = W1t + (size_t)H1 * NIN;           // 128 x 512 bf16
  unsigned char*  ha8   = (unsigned char*)(W2t + (size_t)H2 * H1);   // N_NODES x 128 fp8
  int*            row_ptr = (int*)(ha8 + (size_t)N_NODES * H2);      // N_NODES+1 int

  float* ha_out = (float*)d_out;
  float* hp     = ha_out + (size_t)N_NODES * H2;

  prep_a_kernel<<<2048, 256, 0, stream>>>(seq_a, A1);
  prep_w_kernel<<<1280, 256, 0, stream>>>(W1, W2, W1t, W2t);
  rowptr_kernel<<<2048, 256, 0, stream>>>(adj_rows, row_ptr);
  gemm1_kernel<<<6256, 256, 0, stream>>>(A1, W1t, b1, h_pre);
  gemm2_kernel<<<1564, 256, 0, stream>>>(h_pre, W2t, b2, ha_out, ha8);
  agg_csr_kernel<<<(ROWS_PAD * 64) / 256, 256, 0, stream>>>(row_ptr, adj_cols, adj_vals, ha8, hp);
}

// Round 10
// 287.417 us; speedup vs baseline: 1.4418x; 1.0496x over previous
//
#include <hip/hip_runtime.h>

#define N_NODES 100000
#define ROWS_PAD 100096
#define NIN 512
#define H1  512
#define H2  128
#define N_EDGES 3200000

typedef __attribute__((ext_vector_type(8))) short bf16x8;
typedef __attribute__((ext_vector_type(4))) float f32x4;
typedef __attribute__((ext_vector_type(2))) float f32x2;

__device__ __forceinline__ unsigned short f2b(float x) {
  union { float f; unsigned int u; } c; c.f = x;
  unsigned int u = c.u;
  unsigned int r = (u + 0x7FFFu + ((u >> 16) & 1u)) >> 16;
  return (unsigned short)r;
}

typedef const __attribute__((address_space(1))) unsigned int* gp1_t;
typedef __attribute__((address_space(3))) unsigned int* sp3_t;
__device__ __forceinline__ void gl_lds16(const void* g, void* s) {
  __builtin_amdgcn_global_load_lds((gp1_t)g, (sp3_t)s, 16, 0, 0);
}

// packed f32x2 -> bf16x2 (RNE), 1 VALU inst
__device__ __forceinline__ unsigned cvtpk(float lo, float hi) {
  unsigned r;
  asm("v_cvt_pk_bf16_f32 %0, %1, %2" : "=v"(r) : "v"(lo), "v"(hi));
  return r;
}

// ---- prep_w: W transpose+bf16 pre-swizzled ----
__global__ void prep_w_kernel(const float* __restrict__ W1, const float* __restrict__ W2,
                              unsigned short* __restrict__ W1t, unsigned short* __restrict__ W2t) {
  int idx = blockIdx.x * blockDim.x + threadIdx.x;
  int stride = gridDim.x * blockDim.x;
  for (int i = idx; i < H1 * NIN; i += stride) {
    int n = i >> 9, k = i & 511;
    W1t[i] = f2b(W1[(size_t)(k ^ ((n & 7) << 3)) * H1 + n]);
  }
  for (int i = idx; i < H2 * H1; i += stride) {
    int n = i >> 9, k = i & 511;
    W2t[i] = f2b(W2[(size_t)(k ^ ((n & 7) << 3)) * H2 + n]);
  }
}

// ---- rowptr: row_ptr[r] = first edge index with rows[e] >= r (rows sorted) ----
__global__ void rowptr_kernel(const int* __restrict__ rows, int* __restrict__ row_ptr) {
  int idx = blockIdx.x * blockDim.x + threadIdx.x;
  int stride = gridDim.x * blockDim.x;
  for (int e = idx; e < N_EDGES; e += stride) {
    int r = rows[e];
    int rp = (e == 0) ? -1 : rows[e - 1];
    for (int q = rp + 1; q <= r; ++q) row_ptr[q] = e;
  }
  int lastrow = rows[N_EDGES - 1];
  for (int q = idx; q <= N_NODES; q += stride)
    if (q > lastrow) row_ptr[q] = N_EDGES;
}

// ---- GEMM1: h_pre = relu(seq_a @ W1 + b1); fused f32->bf16 staging, 64x128 tile, XCD swizzle ----
__global__ __launch_bounds__(256, 5) void gemm1_kernel(
    const float* __restrict__ A, const unsigned short* __restrict__ W1t,
    const float* __restrict__ b1, unsigned short* __restrict__ h_pre)
{
  __shared__ __align__(16) unsigned short SM[12288];   // 24 KB: A bf16 [0..4095], B [4096..12287]
  const int tid = threadIdx.x;
  const int w = tid >> 6, lane = tid & 63;
  const int l15 = lane & 15, lg = lane >> 4;
  const int wr = w & 1, wc = w >> 1;
  // bijective XCD swizzle: 6256 = 8 x 782; 4 col-blocks of a row-panel -> same XCD
  const int hw = blockIdx.x;
  const int work = (hw & 7) * 782 + (hw >> 3);
  const int row0 = (work >> 2) << 6;
  const int n0 = (work & 3) << 7;

  // A staging geometry: 4 threads/row, 16 f32 (64B) per thread per kt
  int arow = row0 + (tid >> 2);
  if (arow > N_NODES - 1) arow = N_NODES - 1;           // OOB clamp (stores masked later)
  const float* asrc = A + ((size_t)arow << 9) + ((tid & 3) << 4);
  const int alr  = tid >> 2;                             // local row
  const int aswz = (alr & 7) << 4;
  const int ad0  = ((tid & 3) << 5);                     // 32B of bf16 per thread
  char* alds = (char*)SM + alr * 128;

  f32x4 acc[2][4];
  #pragma unroll
  for (int m = 0; m < 2; ++m)
    #pragma unroll
    for (int n = 0; n < 4; ++n) acc[m][n] = (f32x4){0.f, 0.f, 0.f, 0.f};

  const int so = tid * 16;
  for (int kt = 0; kt < 8; ++kt) {
    // A: 64B f32 -> regs
    const float* ap = asrc + (kt << 6);
    f32x4 a0 = *(const f32x4*)(ap);
    f32x4 a1 = *(const f32x4*)(ap + 4);
    f32x4 a2 = *(const f32x4*)(ap + 8);
    f32x4 a3 = *(const f32x4*)(ap + 12);
    // B: global -> LDS direct
    #pragma unroll
    for (int it = 0; it < 4; ++it) {
      int o = it * 4096 + so;
      int r = o >> 7, kb = o & 127;
      gl_lds16((const char*)W1t + (((size_t)(n0 + r)) << 10) + (kt << 7) + kb, (char*)SM + 8192 + o);
    }
    // convert + swizzled LDS write (2 x b128)
    uint4 w0, w1;
    w0.x = cvtpk(a0[0], a0[1]); w0.y = cvtpk(a0[2], a0[3]);
    w0.z = cvtpk(a1[0], a1[1]); w0.w = cvtpk(a1[2], a1[3]);
    w1.x = cvtpk(a2[0], a2[1]); w1.y = cvtpk(a2[2], a2[3]);
    w1.z = cvtpk(a3[0], a3[1]); w1.w = cvtpk(a3[2], a3[3]);
    *(uint4*)(alds + ((ad0 +  0) ^ aswz)) = w0;
    *(uint4*)(alds + ((ad0 + 16) ^ aswz)) = w1;
    __syncthreads();
    #pragma unroll
    for (int ks = 0; ks < 2; ++ks) {
      bf16x8 af[2], bfr[4];
      #pragma unroll
      for (int m = 0; m < 2; ++m) {
        int r = wr * 32 + m * 16 + l15;
        af[m] = *(const bf16x8*)((const char*)SM + (r << 7) + (((ks << 6) + (lg << 4)) ^ ((r & 7) << 4)));
      }
      #pragma unroll
      for (int n = 0; n < 4; ++n) {
        int r = wc * 64 + n * 16 + l15;
        bfr[n] = *(const bf16x8*)((const char*)SM + 8192 + (r << 7) + (((ks << 6) + (lg << 4)) ^ ((r & 7) << 4)));
      }
      #pragma unroll
      for (int m = 0; m < 2; ++m)
        #pragma unroll
        for (int n = 0; n < 4; ++n)
          acc[m][n] = __builtin_amdgcn_mfma_f32_16x16x32_bf16(af[m], bfr[n], acc[m][n], 0, 0, 0);
    }
    __syncthreads();
  }

  // ---- epilogue: bias+relu -> bf16 (pre-swizzled layout) in LDS, then 16B coalesced stores ----
  #pragma unroll
  for (int n = 0; n < 4; ++n) {
    int cl = wc * 64 + n * 16 + l15;
    float bias = b1[n0 + cl];
    #pragma unroll
    for (int m = 0; m < 2; ++m) {
      #pragma unroll
      for (int q = 0; q < 4; ++q) {
        int rl = wr * 32 + m * 16 + lg * 4 + q;
        float v = acc[m][n][q] + bias;
        v = v > 0.f ? v : 0.f;
        SM[rl * 128 + (cl ^ ((rl & 7) << 3))] = f2b(v);
      }
    }
  }
  __syncthreads();
  #pragma unroll
  for (int p = 0; p < 4; ++p) {
    int ch = tid + p * 256;
    int row = ch >> 4, six = ch & 15;
    uint4 d = *(const uint4*)((const char*)SM + (ch << 4));
    *(uint4*)((char*)h_pre + (((size_t)(row0 + row)) << 10) + (n0 << 1) + (six << 4)) = d;
  }
}

// ---- GEMM2: ha = h_pre @ W2 + b2 -> f32 d_out + fp8 e4m3 gather table; 64x128 tile ----
__global__ __launch_bounds__(256, 5) void gemm2_kernel(
    const unsigned short* __restrict__ Hp, const unsigned short* __restrict__ W2t,
    const float* __restrict__ b2, float* __restrict__ ha_out, unsigned char* __restrict__ ha8)
{
  __shared__ __align__(16) unsigned short SM[12288];
  const int tid = threadIdx.x;
  const int w = tid >> 6, lane = tid & 63;
  const int l15 = lane & 15, lg = lane >> 4;
  const int wr = w & 1, wc = w >> 1;
  const int row0 = blockIdx.x << 6;

  f32x4 acc[2][4];
  #pragma unroll
  for (int m = 0; m < 2; ++m)
    #pragma unroll
    for (int n = 0; n < 4; ++n) acc[m][n] = (f32x4){0.f, 0.f, 0.f, 0.f};

  const int so = tid * 16;
  for (int kt = 0; kt < 8; ++kt) {
    #pragma unroll
    for (int it = 0; it < 2; ++it) {
      int o = it * 4096 + so;
      int r = o >> 7, kb = o & 127;
      gl_lds16((const char*)Hp + (((size_t)(row0 + r)) << 10) + (kt << 7) + kb, (char*)SM + o);
    }
    #pragma unroll
    for (int it = 0; it < 4; ++it) {
      int o = it * 4096 + so;
      int r = o >> 7, kb = o & 127;
      gl_lds16((const char*)W2t + (((size_t)r) << 10) + (kt << 7) + kb, (char*)SM + 8192 + o);
    }
    __syncthreads();
    #pragma unroll
    for (int ks = 0; ks < 2; ++ks) {
      bf16x8 af[2], bfr[4];
      #pragma unroll
      for (int m = 0; m < 2; ++m) {
        int r = wr * 32 + m * 16 + l15;
        af[m] = *(const bf16x8*)((const char*)SM + (r << 7) + (((ks << 6) + (lg << 4)) ^ ((r & 7) << 4)));
      }
      #pragma unroll
      for (int n = 0; n < 4; ++n) {
        int r = wc * 64 + n * 16 + l15;
        bfr[n] = *(const bf16x8*)((const char*)SM + 8192 + (r << 7) + (((ks << 6) + (lg << 4)) ^ ((r & 7) << 4)));
      }
      #pragma unroll
      for (int m = 0; m < 2; ++m)
        #pragma unroll
        for (int n = 0; n < 4; ++n)
          acc[m][n] = __builtin_amdgcn_mfma_f32_16x16x32_bf16(af[m], bfr[n], acc[m][n], 0, 0, 0);
    }
    __syncthreads();
  }

  #pragma unroll
  for (int n = 0; n < 4; ++n) {
    int col = wc * 64 + n * 16 + l15;
    float bias = b2[col];
    #pragma unroll
    for (int m = 0; m < 2; ++m) {
      #pragma unroll
      for (int q = 0; q < 4; ++q) {
        int row = row0 + wr * 32 + m * 16 + lg * 4 + q;
        if (row < N_NODES) {
          float v = acc[m][n][q] + bias;
          ha_out[((size_t)row << 7) + col] = v;
          int p8 = __builtin_amdgcn_cvt_pk_fp8_f32(v, v, 0, false);
          ha8[((size_t)row << 7) + col] = (unsigned char)(p8 & 0xff);
        }
      }
    }
  }
}

// ---- aggregation: CSR, one wave per row, fp8 table (2 cache lines/edge), no atomics ----
__global__ __launch_bounds__(256) void agg_csr_kernel(
    const int* __restrict__ row_ptr, const int* __restrict__ cols, const float* __restrict__ vals,
    const unsigned char* __restrict__ gtab8, float* __restrict__ hp)
{
  const int row = __builtin_amdgcn_readfirstlane((blockIdx.x * blockDim.x + threadIdx.x) >> 6);
  if (row >= N_NODES) return;
  const int lane = threadIdx.x & 63;
  const int e0 = row_ptr[row];
  const int e1 = row_ptr[row + 1];

  float acc0 = 0.f, acc1 = 0.f;
  int e = e0;
  for (; e + 8 <= e1; e += 8) {
    int c[8]; float v[8]; unsigned short g[8];
    #pragma unroll
    for (int j = 0; j < 8; ++j) { c[j] = cols[e + j]; v[j] = vals[e + j]; }
    #pragma unroll
    for (int j = 0; j < 8; ++j)
      g[j] = *(const unsigned short*)(gtab8 + ((size_t)c[j] << 7) + (lane << 1));
    float t0 = acc0, t1 = 0.f, u0 = acc1, u1 = 0.f;
    #pragma unroll
    for (int j = 0; j < 8; j += 2) {
      f32x2 f0 = __builtin_amdgcn_cvt_pk_f32_fp8((int)g[j+0], false);
      f32x2 f1 = __builtin_amdgcn_cvt_pk_f32_fp8((int)g[j+1], false);
      t0 = fmaf(v[j+0], f0.x, t0);
      t1 = fmaf(v[j+1], f1.x, t1);
      u0 = fmaf(v[j+0], f0.y, u0);
      u1 = fmaf(v[j+1], f1.y, u1);
    }
    acc0 = t0 + t1; acc1 = u0 + u1;
  }
  for (; e < e1; ++e) {
    int c = cols[e];
    float v = vals[e];
    unsigned short g = *(const unsigned short*)(gtab8 + ((size_t)c << 7) + (lane << 1));
    f32x2 f = __builtin_amdgcn_cvt_pk_f32_fp8((int)g, false);
    acc0 = fmaf(v, f.x, acc0);
    acc1 = fmaf(v, f.y, acc1);
  }
  float2 st; st.x = acc0; st.y = acc1;
  *(float2*)&hp[((size_t)row << 7) + (lane << 1)] = st;
}

extern "C" void kernel_launch(void* const* d_in, const int* in_sizes, int n_in,
                              void* d_out, int out_size, void* d_ws, size_t ws_size,
                              hipStream_t stream) {
  const float* seq_a    = (const float*)d_in[0];
  const float* W1       = (const float*)d_in[1];
  const float* b1       = (const float*)d_in[2];
  const float* W2       = (const float*)d_in[3];
  const float* b2       = (const float*)d_in[4];
  const int*   adj_rows = (const int*)d_in[5];
  const int*   adj_cols = (const int*)d_in[6];
  const float* adj_vals = (const float*)d_in[7];

  unsigned short* h_pre = (unsigned short*)d_ws;            // ROWS_PAD x 512 bf16 (swizzled)
  unsigned short* W1t   = h_pre + (size_t)ROWS_PAD * H1;    // 512 x 512 bf16
  unsigned short* W2t   = W1t + (size_t)H1 * NIN;           // 128 x 512 bf16
  unsigned char*  ha8   = (unsigned char*)(W2t + (size_t)H2 * H1);   // N_NODES x 128 fp8
  int*            row_ptr = (int*)(ha8 + (size_t)N_NODES * H2);      // N_NODES+1 int

  float* ha_out = (float*)d_out;
  float* hp     = ha_out + (size_t)N_NODES * H2;

  prep_w_kernel<<<1280, 256, 0, stream>>>(W1, W2, W1t, W2t);
  rowptr_kernel<<<2048, 256, 0, stream>>>(adj_rows, row_ptr);
  gemm1_kernel<<<6256, 256, 0, stream>>>(seq_a, W1t, b1, h_pre);
  gemm2_kernel<<<1564, 256, 0, stream>>>(h_pre, W2t, b2, ha_out, ha8);
  agg_csr_kernel<<<(ROWS_PAD * 64) / 256, 256, 0, stream>>>(row_ptr, adj_cols, adj_vals, ha8, hp);
}

// Round 11
// 259.102 us; speedup vs baseline: 1.5994x; 1.1093x over previous
//
#include <hip/hip_runtime.h>

#define N_NODES 100000
#define ROWS_PAD 100096
#define NIN 512
#define H1  512
#define H2  128
#define N_EDGES 3200000

typedef __attribute__((ext_vector_type(8))) short bf16x8;
typedef __attribute__((ext_vector_type(4))) float f32x4;
typedef __attribute__((ext_vector_type(2))) float f32x2;

__device__ __forceinline__ unsigned short f2b(float x) {
  union { float f; unsigned int u; } c; c.f = x;
  unsigned int u = c.u;
  unsigned int r = (u + 0x7FFFu + ((u >> 16) & 1u)) >> 16;
  return (unsigned short)r;
}

typedef const __attribute__((address_space(1))) unsigned int* gp1_t;
typedef __attribute__((address_space(3))) unsigned int* sp3_t;
__device__ __forceinline__ void gl_lds16(const void* g, void* s) {
  __builtin_amdgcn_global_load_lds((gp1_t)g, (sp3_t)s, 16, 0, 0);
}

// packed f32x2 -> bf16x2 (RNE), 1 VALU inst
__device__ __forceinline__ unsigned cvtpk(float lo, float hi) {
  unsigned r;
  asm("v_cvt_pk_bf16_f32 %0, %1, %2" : "=v"(r) : "v"(lo), "v"(hi));
  return r;
}

// ---- prep_w: W transpose+bf16 pre-swizzled ----
__global__ void prep_w_kernel(const float* __restrict__ W1, const float* __restrict__ W2,
                              unsigned short* __restrict__ W1t, unsigned short* __restrict__ W2t) {
  int idx = blockIdx.x * blockDim.x + threadIdx.x;
  int stride = gridDim.x * blockDim.x;
  for (int i = idx; i < H1 * NIN; i += stride) {
    int n = i >> 9, k = i & 511;
    W1t[i] = f2b(W1[(size_t)(k ^ ((n & 7) << 3)) * H1 + n]);
  }
  for (int i = idx; i < H2 * H1; i += stride) {
    int n = i >> 9, k = i & 511;
    W2t[i] = f2b(W2[(size_t)(k ^ ((n & 7) << 3)) * H2 + n]);
  }
}

// ---- rowptr: row_ptr[r] = first edge index with rows[e] >= r (rows sorted) ----
__global__ void rowptr_kernel(const int* __restrict__ rows, int* __restrict__ row_ptr) {
  int idx = blockIdx.x * blockDim.x + threadIdx.x;
  int stride = gridDim.x * blockDim.x;
  for (int e = idx; e < N_EDGES; e += stride) {
    int r = rows[e];
    int rp = (e == 0) ? -1 : rows[e - 1];
    for (int q = rp + 1; q <= r; ++q) row_ptr[q] = e;
  }
  int lastrow = rows[N_EDGES - 1];
  for (int q = idx; q <= N_NODES; q += stride)
    if (q > lastrow) row_ptr[q] = N_EDGES;
}

// ---- GEMM1: h_pre = relu(seq_a @ W1 + b1); fused f32->bf16 staging with A-reg prefetch ----
__global__ __launch_bounds__(256, 5) void gemm1_kernel(
    const float* __restrict__ A, const unsigned short* __restrict__ W1t,
    const float* __restrict__ b1, unsigned short* __restrict__ h_pre)
{
  __shared__ __align__(16) unsigned short SM[12288];   // 24 KB: A bf16 [0..4095], B [4096..12287]
  const int tid = threadIdx.x;
  const int w = tid >> 6, lane = tid & 63;
  const int l15 = lane & 15, lg = lane >> 4;
  const int wr = w & 1, wc = w >> 1;
  // bijective XCD swizzle: 6256 = 8 x 782; 4 col-blocks of a row-panel -> same XCD
  const int hw = blockIdx.x;
  const int work = (hw & 7) * 782 + (hw >> 3);
  const int row0 = (work >> 2) << 6;
  const int n0 = (work & 3) << 7;

  // A staging geometry: 4 threads/row, 16 f32 (64B) per thread per kt
  int arow = row0 + (tid >> 2);
  if (arow > N_NODES - 1) arow = N_NODES - 1;           // OOB clamp (stores masked later)
  const float* asrc = A + ((size_t)arow << 9) + ((tid & 3) << 4);
  const int alr  = tid >> 2;
  const int aswz = (alr & 7) << 4;
  const int ad0  = ((tid & 3) << 5);
  char* alds = (char*)SM + alr * 128;

  f32x4 acc[2][4];
  #pragma unroll
  for (int m = 0; m < 2; ++m)
    #pragma unroll
    for (int n = 0; n < 4; ++n) acc[m][n] = (f32x4){0.f, 0.f, 0.f, 0.f};

  const int so = tid * 16;

  // preload A regs for kt=0 (oldest vmem ops)
  f32x4 a0 = *(const f32x4*)(asrc);
  f32x4 a1 = *(const f32x4*)(asrc + 4);
  f32x4 a2 = *(const f32x4*)(asrc + 8);
  f32x4 a3 = *(const f32x4*)(asrc + 12);

  #pragma unroll
  for (int kt = 0; kt < 8; ++kt) {
    // B: global -> LDS direct (4 ops; drained at the pre-MFMA barrier)
    #pragma unroll
    for (int it = 0; it < 4; ++it) {
      int o = it * 4096 + so;
      int r = o >> 7, kb = o & 127;
      gl_lds16((const char*)W1t + (((size_t)(n0 + r)) << 10) + (kt << 7) + kb, (char*)SM + 8192 + o);
    }
    // convert cur A regs (compiler waits the 4 oldest = A(kt); B stays in flight)
    uint4 w0, w1;
    w0.x = cvtpk(a0[0], a0[1]); w0.y = cvtpk(a0[2], a0[3]);
    w0.z = cvtpk(a1[0], a1[1]); w0.w = cvtpk(a1[2], a1[3]);
    w1.x = cvtpk(a2[0], a2[1]); w1.y = cvtpk(a2[2], a2[3]);
    w1.z = cvtpk(a3[0], a3[1]); w1.w = cvtpk(a3[2], a3[3]);
    *(uint4*)(alds + ((ad0 +  0) ^ aswz)) = w0;
    *(uint4*)(alds + ((ad0 + 16) ^ aswz)) = w1;
    // prefetch A regs for kt+1 as the NEWEST vmem ops, left in flight across MFMA
    __builtin_amdgcn_sched_barrier(0);
    if (kt < 7) {
      const float* anp = asrc + ((kt + 1) << 6);
      a0 = *(const f32x4*)(anp);
      a1 = *(const f32x4*)(anp + 4);
      a2 = *(const f32x4*)(anp + 8);
      a3 = *(const f32x4*)(anp + 12);
      __builtin_amdgcn_sched_barrier(0);
      asm volatile("s_waitcnt vmcnt(4) lgkmcnt(0)" ::: "memory");  // drain B + ds_writes, keep A(kt+1)
    } else {
      __builtin_amdgcn_sched_barrier(0);
      asm volatile("s_waitcnt vmcnt(0) lgkmcnt(0)" ::: "memory");
    }
    __builtin_amdgcn_s_barrier();
    __builtin_amdgcn_sched_barrier(0);
    #pragma unroll
    for (int ks = 0; ks < 2; ++ks) {
      bf16x8 af[2], bfr[4];
      #pragma unroll
      for (int m = 0; m < 2; ++m) {
        int r = wr * 32 + m * 16 + l15;
        af[m] = *(const bf16x8*)((const char*)SM + (r << 7) + (((ks << 6) + (lg << 4)) ^ ((r & 7) << 4)));
      }
      #pragma unroll
      for (int n = 0; n < 4; ++n) {
        int r = wc * 64 + n * 16 + l15;
        bfr[n] = *(const bf16x8*)((const char*)SM + 8192 + (r << 7) + (((ks << 6) + (lg << 4)) ^ ((r & 7) << 4)));
      }
      #pragma unroll
      for (int m = 0; m < 2; ++m)
        #pragma unroll
        for (int n = 0; n < 4; ++n)
          acc[m][n] = __builtin_amdgcn_mfma_f32_16x16x32_bf16(af[m], bfr[n], acc[m][n], 0, 0, 0);
    }
    __builtin_amdgcn_sched_barrier(0);
    __builtin_amdgcn_s_barrier();   // all waves' ds_reads retired before next kt's writes
  }

  // ---- epilogue: bias+relu -> bf16 (pre-swizzled layout) in LDS, then 16B coalesced stores ----
  #pragma unroll
  for (int n = 0; n < 4; ++n) {
    int cl = wc * 64 + n * 16 + l15;
    float bias = b1[n0 + cl];
    #pragma unroll
    for (int m = 0; m < 2; ++m) {
      #pragma unroll
      for (int q = 0; q < 4; ++q) {
        int rl = wr * 32 + m * 16 + lg * 4 + q;
        float v = acc[m][n][q] + bias;
        v = v > 0.f ? v : 0.f;
        SM[rl * 128 + (cl ^ ((rl & 7) << 3))] = f2b(v);
      }
    }
  }
  __syncthreads();
  #pragma unroll
  for (int p = 0; p < 4; ++p) {
    int ch = tid + p * 256;
    int row = ch >> 4, six = ch & 15;
    uint4 d = *(const uint4*)((const char*)SM + (ch << 4));
    *(uint4*)((char*)h_pre + (((size_t)(row0 + row)) << 10) + (n0 << 1) + (six << 4)) = d;
  }
}

// ---- GEMM2: ha = h_pre @ W2 + b2 -> f32 d_out + fp8 e4m3 gather table; 64x128 tile ----
__global__ __launch_bounds__(256, 5) void gemm2_kernel(
    const unsigned short* __restrict__ Hp, const unsigned short* __restrict__ W2t,
    const float* __restrict__ b2, float* __restrict__ ha_out, unsigned char* __restrict__ ha8)
{
  __shared__ __align__(16) unsigned short SM[12288];
  const int tid = threadIdx.x;
  const int w = tid >> 6, lane = tid & 63;
  const int l15 = lane & 15, lg = lane >> 4;
  const int wr = w & 1, wc = w >> 1;
  const int row0 = blockIdx.x << 6;

  f32x4 acc[2][4];
  #pragma unroll
  for (int m = 0; m < 2; ++m)
    #pragma unroll
    for (int n = 0; n < 4; ++n) acc[m][n] = (f32x4){0.f, 0.f, 0.f, 0.f};

  const int so = tid * 16;
  for (int kt = 0; kt < 8; ++kt) {
    #pragma unroll
    for (int it = 0; it < 2; ++it) {
      int o = it * 4096 + so;
      int r = o >> 7, kb = o & 127;
      gl_lds16((const char*)Hp + (((size_t)(row0 + r)) << 10) + (kt << 7) + kb, (char*)SM + o);
    }
    #pragma unroll
    for (int it = 0; it < 4; ++it) {
      int o = it * 4096 + so;
      int r = o >> 7, kb = o & 127;
      gl_lds16((const char*)W2t + (((size_t)r) << 10) + (kt << 7) + kb, (char*)SM + 8192 + o);
    }
    __syncthreads();
    #pragma unroll
    for (int ks = 0; ks < 2; ++ks) {
      bf16x8 af[2], bfr[4];
      #pragma unroll
      for (int m = 0; m < 2; ++m) {
        int r = wr * 32 + m * 16 + l15;
        af[m] = *(const bf16x8*)((const char*)SM + (r << 7) + (((ks << 6) + (lg << 4)) ^ ((r & 7) << 4)));
      }
      #pragma unroll
      for (int n = 0; n < 4; ++n) {
        int r = wc * 64 + n * 16 + l15;
        bfr[n] = *(const bf16x8*)((const char*)SM + 8192 + (r << 7) + (((ks << 6) + (lg << 4)) ^ ((r & 7) << 4)));
      }
      #pragma unroll
      for (int m = 0; m < 2; ++m)
        #pragma unroll
        for (int n = 0; n < 4; ++n)
          acc[m][n] = __builtin_amdgcn_mfma_f32_16x16x32_bf16(af[m], bfr[n], acc[m][n], 0, 0, 0);
    }
    __syncthreads();
  }

  #pragma unroll
  for (int n = 0; n < 4; ++n) {
    int col = wc * 64 + n * 16 + l15;
    float bias = b2[col];
    #pragma unroll
    for (int m = 0; m < 2; ++m) {
      #pragma unroll
      for (int q = 0; q < 4; ++q) {
        int row = row0 + wr * 32 + m * 16 + lg * 4 + q;
        if (row < N_NODES) {
          float v = acc[m][n][q] + bias;
          ha_out[((size_t)row << 7) + col] = v;
          int p8 = __builtin_amdgcn_cvt_pk_fp8_f32(v, v, 0, false);
          ha8[((size_t)row << 7) + col] = (unsigned char)(p8 & 0xff);
        }
      }
    }
  }
}

// ---- aggregation: CSR, one wave per row, fp8 table (2 cache lines/edge), no atomics ----
__global__ __launch_bounds__(256) void agg_csr_kernel(
    const int* __restrict__ row_ptr, const int* __restrict__ cols, const float* __restrict__ vals,
    const unsigned char* __restrict__ gtab8, float* __restrict__ hp)
{
  const int row = __builtin_amdgcn_readfirstlane((blockIdx.x * blockDim.x + threadIdx.x) >> 6);
  if (row >= N_NODES) return;
  const int lane = threadIdx.x & 63;
  const int e0 = row_ptr[row];
  const int e1 = row_ptr[row + 1];

  float acc0 = 0.f, acc1 = 0.f;
  int e = e0;
  for (; e + 8 <= e1; e += 8) {
    int c[8]; float v[8]; unsigned short g[8];
    #pragma unroll
    for (int j = 0; j < 8; ++j) { c[j] = cols[e + j]; v[j] = vals[e + j]; }
    #pragma unroll
    for (int j = 0; j < 8; ++j)
      g[j] = *(const unsigned short*)(gtab8 + ((size_t)c[j] << 7) + (lane << 1));
    float t0 = acc0, t1 = 0.f, u0 = acc1, u1 = 0.f;
    #pragma unroll
    for (int j = 0; j < 8; j += 2) {
      f32x2 f0 = __builtin_amdgcn_cvt_pk_f32_fp8((int)g[j+0], false);
      f32x2 f1 = __builtin_amdgcn_cvt_pk_f32_fp8((int)g[j+1], false);
      t0 = fmaf(v[j+0], f0.x, t0);
      t1 = fmaf(v[j+1], f1.x, t1);
      u0 = fmaf(v[j+0], f0.y, u0);
      u1 = fmaf(v[j+1], f1.y, u1);
    }
    acc0 = t0 + t1; acc1 = u0 + u1;
  }
  for (; e < e1; ++e) {
    int c = cols[e];
    float v = vals[e];
    unsigned short g = *(const unsigned short*)(gtab8 + ((size_t)c << 7) + (lane << 1));
    f32x2 f = __builtin_amdgcn_cvt_pk_f32_fp8((int)g, false);
    acc0 = fmaf(v, f.x, acc0);
    acc1 = fmaf(v, f.y, acc1);
  }
  float2 st; st.x = acc0; st.y = acc1;
  *(float2*)&hp[((size_t)row << 7) + (lane << 1)] = st;
}

extern "C" void kernel_launch(void* const* d_in, const int* in_sizes, int n_in,
                              void* d_out, int out_size, void* d_ws, size_t ws_size,
                              hipStream_t stream) {
  const float* seq_a    = (const float*)d_in[0];
  const float* W1       = (const float*)d_in[1];
  const float* b1       = (const float*)d_in[2];
  const float* W2       = (const float*)d_in[3];
  const float* b2       = (const float*)d_in[4];
  const int*   adj_rows = (const int*)d_in[5];
  const int*   adj_cols = (const int*)d_in[6];
  const float* adj_vals = (const float*)d_in[7];

  unsigned short* h_pre = (unsigned short*)d_ws;            // ROWS_PAD x 512 bf16 (swizzled)
  unsigned short* W1t   = h_pre + (size_t)ROWS_PAD * H1;    // 512 x 512 bf16
  unsigned short* W2t   = W1t + (size_t)H1 * NIN;           // 128 x 512 bf16
  unsigned char*  ha8   = (unsigned char*)(W2t + (size_t)H2 * H1);   // N_NODES x 128 fp8
  int*            row_ptr = (int*)(ha8 + (size_t)N_NODES * H2);      // N_NODES+1 int

  float* ha_out = (float*)d_out;
  float* hp     = ha_out + (size_t)N_NODES * H2;

  prep_w_kernel<<<1280, 256, 0, stream>>>(W1, W2, W1t, W2t);
  rowptr_kernel<<<2048, 256, 0, stream>>>(adj_rows, row_ptr);
  gemm1_kernel<<<6256, 256, 0, stream>>>(seq_a, W1t, b1, h_pre);
  gemm2_kernel<<<1564, 256, 0, stream>>>(h_pre, W2t, b2, ha_out, ha8);
  agg_csr_kernel<<<(ROWS_PAD * 64) / 256, 256, 0, stream>>>(row_ptr, adj_cols, adj_vals, ha8, hp);
}